// Round 1
// baseline (124.650 us; speedup 1.0000x reference)
//
#include <hip/hip_runtime.h>
#include <hip/hip_bf16.h>

#define NROWS 8192   // 2B
#define HALFB 4096   // B
#define DIMK  256    // D
#define BM    128
#define BN    128
#define CHUNKS 8               // column chunks of BN per block
#define COLGROUPS 8            // NROWS / (BN*CHUNKS)
#define ROWTILES  64           // NROWS / BM

typedef __attribute__((ext_vector_type(4))) float f32x4;
typedef __attribute__((ext_vector_type(8))) short short8;

__device__ __forceinline__ unsigned short f2bf(float f) {
  unsigned u = __float_as_uint(f);
  u += 0x7fffu + ((u >> 16) & 1u);   // RNE
  return (unsigned short)(u >> 16);
}

// ---------------- kernel 1: row normalize, fp32 -> bf16, store 1/max(norm,eps)
__global__ __launch_bounds__(256) void k_normalize(const float* __restrict__ zi,
                                                   const float* __restrict__ zj,
                                                   unsigned short* __restrict__ zn,
                                                   float* __restrict__ rnorm) {
  const int row  = blockIdx.x * 4 + (threadIdx.x >> 6);
  const int lane = threadIdx.x & 63;
  const float* src = (row < HALFB) ? (zi + (size_t)row * DIMK)
                                   : (zj + (size_t)(row - HALFB) * DIMK);
  float4 v = reinterpret_cast<const float4*>(src)[lane];
  float ss = v.x * v.x + v.y * v.y + v.z * v.z + v.w * v.w;
#pragma unroll
  for (int m = 1; m < 64; m <<= 1) ss += __shfl_xor(ss, m, 64);
  const float rs = 1.0f / fmaxf(sqrtf(ss), 1e-8f);
  if (lane == 0) rnorm[row] = rs;
  ushort4 o;
  o.x = f2bf(v.x * rs); o.y = f2bf(v.y * rs);
  o.z = f2bf(v.z * rs); o.w = f2bf(v.w * rs);
  reinterpret_cast<ushort4*>(zn + (size_t)row * DIMK)[lane] = o;
}

// ---------------- kernel 2: positives (exact fp32 dot of z_i[k] . z_j[k])
__global__ __launch_bounds__(256) void k_pos(const float* __restrict__ zi,
                                             const float* __restrict__ zj,
                                             const float* __restrict__ rnorm,
                                             float* __restrict__ pos) {
  const int k    = blockIdx.x * 4 + (threadIdx.x >> 6);
  const int lane = threadIdx.x & 63;
  float4 a = reinterpret_cast<const float4*>(zi + (size_t)k * DIMK)[lane];
  float4 b = reinterpret_cast<const float4*>(zj + (size_t)k * DIMK)[lane];
  float d = a.x * b.x + a.y * b.y + a.z * b.z + a.w * b.w;
#pragma unroll
  for (int m = 1; m < 64; m <<= 1) d += __shfl_xor(d, m, 64);
  if (lane == 0) {
    const float p = d * rnorm[k] * rnorm[k + HALFB] * 2.0f;  // /T = *2
    pos[k] = p;
    pos[k + HALFB] = p;
  }
}

// ---------------- staging: 128 rows x 512B, XOR-swizzled global source,
// linear LDS dest via global_load_lds (width 16). swz(row) = (row&7)<<4.
__device__ __forceinline__ void stage128x256(const unsigned short* __restrict__ g,
                                             unsigned short* lds, int wave, int lane) {
#pragma unroll
  for (int i = 0; i < 16; ++i) {
    const int chunk = i * 4 + wave;          // 1KB chunk index, wave-uniform
    const int row = chunk * 2 + (lane >> 5); // 2 rows (512B each) per chunk
    const int srcByte = row * 512 + (((lane & 31) << 4) ^ ((row & 7) << 4));
    __builtin_amdgcn_global_load_lds(
        (const __attribute__((address_space(1))) void*)(reinterpret_cast<const char*>(g) + srcByte),
        (__attribute__((address_space(3))) void*)(reinterpret_cast<char*>(lds) + chunk * 1024),
        16, 0, 0);
  }
}

__device__ __forceinline__ short8 ldsFrag(const unsigned short* lds, int row, int byteoff) {
  const int addr = row * 512 + (byteoff ^ ((row & 7) << 4));
  return *reinterpret_cast<const short8*>(reinterpret_cast<const char*>(lds) + addr);
}

// ---------------- kernel 3: fused sim = zn.zn^T * 2, exp, diag-mask, row-sum
__global__ __launch_bounds__(256) void k_simexp(const unsigned short* __restrict__ zn,
                                                float* __restrict__ denom) {
  __shared__ __align__(16) unsigned short ldsA[BM * DIMK];  // 64 KB
  __shared__ __align__(16) unsigned short ldsB[BN * DIMK];  // 64 KB

  const int tid  = threadIdx.x;
  const int lane = tid & 63;
  const int wave = tid >> 6;
  const int wm = wave >> 1, wn = wave & 1;   // 2x2 waves, 64x64 each

  const int rowTile      = blockIdx.x / COLGROUPS;
  const int colGroup     = blockIdx.x % COLGROUPS;
  const int rowBase      = rowTile * BM;
  const int colGroupBase = colGroup * (BN * CHUNKS);

  stage128x256(zn + (size_t)rowBase * DIMK, ldsA, wave, lane);
  stage128x256(zn + (size_t)colGroupBase * DIMK, ldsB, wave, lane);

  float sums[4][4];
#pragma unroll
  for (int m = 0; m < 4; ++m)
#pragma unroll
    for (int r = 0; r < 4; ++r) sums[m][r] = 0.0f;

  for (int c = 0; c < CHUNKS; ++c) {
    __syncthreads();   // staging (incl. vmcnt drain) done

    f32x4 acc[4][4];
#pragma unroll
    for (int m = 0; m < 4; ++m)
#pragma unroll
      for (int n = 0; n < 4; ++n) acc[m][n] = (f32x4){0.f, 0.f, 0.f, 0.f};

#pragma unroll
    for (int kk = 0; kk < 8; ++kk) {
      short8 af[4], bfr[4];
      const int bo = (kk << 6) + ((lane >> 4) << 4);
#pragma unroll
      for (int m = 0; m < 4; ++m)
        af[m] = ldsFrag(ldsA, wm * 64 + m * 16 + (lane & 15), bo);
#pragma unroll
      for (int n = 0; n < 4; ++n)
        bfr[n] = ldsFrag(ldsB, wn * 64 + n * 16 + (lane & 15), bo);
#pragma unroll
      for (int m = 0; m < 4; ++m)
#pragma unroll
        for (int n = 0; n < 4; ++n)
          acc[m][n] = __builtin_amdgcn_mfma_f32_16x16x32_bf16(af[m], bfr[n], acc[m][n], 0, 0, 0);
    }

    // epilogue: *2 (1/T), exp, mask diagonal, accumulate per-lane row partials
    const int colChunk = colGroupBase + c * BN;
#pragma unroll
    for (int m = 0; m < 4; ++m) {
      const int grow = rowBase + wm * 64 + m * 16 + ((lane >> 4) << 2);
#pragma unroll
      for (int n = 0; n < 4; ++n) {
        const int gcol = colChunk + wn * 64 + n * 16 + (lane & 15);
#pragma unroll
        for (int r = 0; r < 4; ++r) {
          float e = __expf(acc[m][n][r] * 2.0f);
          if (grow + r == gcol) e = 0.0f;   // exact diagonal mask
          sums[m][r] += e;
        }
      }
    }

    __syncthreads();   // all waves done reading ldsB
    if (c + 1 < CHUNKS)
      stage128x256(zn + (size_t)(colGroupBase + (c + 1) * BN) * DIMK, ldsB, wave, lane);
  }

  // complete row sums: reduce over the 16 lanes holding the same rows
#pragma unroll
  for (int m = 0; m < 4; ++m)
#pragma unroll
    for (int r = 0; r < 4; ++r) {
      float s = sums[m][r];
      s += __shfl_xor(s, 1, 64);
      s += __shfl_xor(s, 2, 64);
      s += __shfl_xor(s, 4, 64);
      s += __shfl_xor(s, 8, 64);
      if ((lane & 15) == 0)
        atomicAdd(&denom[rowBase + wm * 64 + m * 16 + ((lane >> 4) << 2) + r], s);
    }
}

// ---------------- kernel 4: loss = mean(log(denom) - pos)
__global__ __launch_bounds__(256) void k_finalize(const float* __restrict__ denom,
                                                  const float* __restrict__ pos,
                                                  float* __restrict__ out) {
  const int t = threadIdx.x;
  float s = 0.0f;
  for (int i = t; i < NROWS; i += 256) s += __logf(denom[i]) - pos[i];
#pragma unroll
  for (int m = 1; m < 64; m <<= 1) s += __shfl_xor(s, m, 64);
  __shared__ float partial[4];
  if ((t & 63) == 0) partial[t >> 6] = s;
  __syncthreads();
  if (t == 0)
    out[0] = (partial[0] + partial[1] + partial[2] + partial[3]) * (1.0f / (float)NROWS);
}

extern "C" void kernel_launch(void* const* d_in, const int* in_sizes, int n_in,
                              void* d_out, int out_size, void* d_ws, size_t ws_size,
                              hipStream_t stream) {
  const float* zi = (const float*)d_in[0];
  const float* zj = (const float*)d_in[1];
  float* out = (float*)d_out;

  char* ws = (char*)d_ws;
  unsigned short* zn = (unsigned short*)ws;                       // 4 MiB bf16
  float* rnorm = (float*)(ws + (size_t)NROWS * DIMK * 2);         // 32 KB
  float* pos   = rnorm + NROWS;                                   // 32 KB
  float* denom = pos + NROWS;                                     // 32 KB

  hipMemsetAsync(denom, 0, NROWS * sizeof(float), stream);
  k_normalize<<<NROWS / 4, 256, 0, stream>>>(zi, zj, zn, rnorm);
  k_pos<<<HALFB / 4, 256, 0, stream>>>(zi, zj, rnorm, pos);
  k_simexp<<<ROWTILES * COLGROUPS, 256, 0, stream>>>(zn, denom);
  k_finalize<<<1, 256, 0, stream>>>(denom, pos, out);
}

// Round 2
// 114.386 us; speedup vs baseline: 1.0897x; 1.0897x over previous
//
#include <hip/hip_runtime.h>
#include <hip/hip_bf16.h>

#define NROWS 8192   // 2B
#define HALFB 4096   // B
#define DIMK  256    // D
// scale folded into zn: sim_acc = cos * 2*log2(e)  ->  exp2(acc) = exp(cos/T)
#define SCALE 1.6986436f   // sqrt(2*log2(e)) = sqrt(2.8853901)

typedef __attribute__((ext_vector_type(4))) float f32x4;
typedef __attribute__((ext_vector_type(8))) short short8;

__device__ __forceinline__ unsigned short f2bf(float f) {
  unsigned u = __float_as_uint(f);
  u += 0x7fffu + ((u >> 16) & 1u);   // RNE
  return (unsigned short)(u >> 16);
}

// ---------------- kernel 1: normalize both rows of pair k + exact fp32 positive
__global__ __launch_bounds__(256) void k_normpos(const float* __restrict__ zi,
                                                 const float* __restrict__ zj,
                                                 unsigned short* __restrict__ zn,
                                                 float* __restrict__ pos) {
  const int k    = blockIdx.x * 4 + (threadIdx.x >> 6);
  const int lane = threadIdx.x & 63;
  float4 a = reinterpret_cast<const float4*>(zi + (size_t)k * DIMK)[lane];
  float4 b = reinterpret_cast<const float4*>(zj + (size_t)k * DIMK)[lane];
  float ssa = a.x * a.x + a.y * a.y + a.z * a.z + a.w * a.w;
  float ssb = b.x * b.x + b.y * b.y + b.z * b.z + b.w * b.w;
  float dot = a.x * b.x + a.y * b.y + a.z * b.z + a.w * b.w;
#pragma unroll
  for (int m = 1; m < 64; m <<= 1) {
    ssa += __shfl_xor(ssa, m, 64);
    ssb += __shfl_xor(ssb, m, 64);
    dot += __shfl_xor(dot, m, 64);
  }
  const float ra = 1.0f / fmaxf(sqrtf(ssa), 1e-8f);
  const float rb = 1.0f / fmaxf(sqrtf(ssb), 1e-8f);
  const float sa = ra * SCALE, sb = rb * SCALE;
  ushort4 oa, ob;
  oa.x = f2bf(a.x * sa); oa.y = f2bf(a.y * sa); oa.z = f2bf(a.z * sa); oa.w = f2bf(a.w * sa);
  ob.x = f2bf(b.x * sb); ob.y = f2bf(b.y * sb); ob.z = f2bf(b.z * sb); ob.w = f2bf(b.w * sb);
  reinterpret_cast<ushort4*>(zn + (size_t)k * DIMK)[lane] = oa;
  reinterpret_cast<ushort4*>(zn + (size_t)(k + HALFB) * DIMK)[lane] = ob;
  if (lane == 0) {
    const float p = dot * ra * rb * 2.0f;   // exact fp32, /T = *2
    pos[k] = p;
    pos[k + HALFB] = p;
  }
}

// ---------------- staging: 128 rows x 512B, XOR-swizzled global source,
// linear LDS dest via global_load_lds (width 16). swz(row) = (row&7)<<4.
__device__ __forceinline__ void stage128x256(const unsigned short* __restrict__ g,
                                             unsigned short* lds, int wave, int lane) {
#pragma unroll
  for (int i = 0; i < 16; ++i) {
    const int chunk = i * 4 + wave;          // 1KB chunk index, wave-uniform
    const int row = chunk * 2 + (lane >> 5); // 2 rows (512B each) per chunk
    const int srcByte = row * 512 + (((lane & 31) << 4) ^ ((row & 7) << 4));
    __builtin_amdgcn_global_load_lds(
        (const __attribute__((address_space(1))) void*)(reinterpret_cast<const char*>(g) + srcByte),
        (__attribute__((address_space(3))) void*)(reinterpret_cast<char*>(lds) + chunk * 1024),
        16, 0, 0);
  }
}

__device__ __forceinline__ short8 ldsFrag(const unsigned short* lds, int row, int byteoff) {
  const int addr = row * 512 + (byteoff ^ ((row & 7) << 4));
  return *reinterpret_cast<const short8*>(reinterpret_cast<const char*>(lds) + addr);
}

// ---------------- kernel 2: fused sim/exp/rowsum.
// Block = 256 rows x 1024 cols (8 chunks of 128). 4 waves; wave = 64 rows x 128 cols.
// A in registers (full K), B double-buffered in LDS.
__global__ __launch_bounds__(256, 1) void k_simexp(const unsigned short* __restrict__ zn,
                                                   float* __restrict__ part) {
  __shared__ __align__(16) unsigned short ldsB[2][128 * DIMK];   // 2 x 64 KB

  const int tid  = threadIdx.x;
  const int lane = tid & 63;
  const int wv   = tid >> 6;
  const int r = blockIdx.x >> 3;          // row band (256 rows)
  const int s = blockIdx.x & 7;           // col group (1024 cols)
  const int rowBase      = r << 8;
  const int colGroupBase = s << 10;

  // stage chunk 0 into buf0
  stage128x256(zn + (size_t)colGroupBase * DIMK, ldsB[0], wv, lane);

  // A fragments for this wave's 64 rows, full K=256, in registers (128 VGPRs)
  short8 af[4][8];
  const int arow0 = rowBase + wv * 64 + (lane & 15);
  const int koff  = (lane >> 4) << 3;     // k sub-offset within frag
#pragma unroll
  for (int m = 0; m < 4; ++m)
#pragma unroll
    for (int kk = 0; kk < 8; ++kk)
      af[m][kk] = *reinterpret_cast<const short8*>(
          zn + (size_t)(arow0 + m * 16) * DIMK + kk * 32 + koff);

  float sums[4][4];
#pragma unroll
  for (int m = 0; m < 4; ++m)
#pragma unroll
    for (int rr = 0; rr < 4; ++rr) sums[m][rr] = 0.0f;

  __syncthreads();   // buf0 staged (drains vmcnt), A regs loaded

  for (int c = 0; c < 8; ++c) {
    const unsigned short* bcur = ldsB[c & 1];
    if (c < 7)   // prefetch next chunk into other buffer; drained at end of this chunk
      stage128x256(zn + (size_t)(colGroupBase + (c + 1) * 128) * DIMK, ldsB[(c + 1) & 1], wv, lane);

    f32x4 acc[4][8];
#pragma unroll
    for (int m = 0; m < 4; ++m)
#pragma unroll
      for (int n = 0; n < 8; ++n) acc[m][n] = (f32x4){0.f, 0.f, 0.f, 0.f};

#pragma unroll
    for (int kk = 0; kk < 8; ++kk) {
      short8 bfr[8];
      const int bo = (kk << 6) + ((lane >> 4) << 4);
#pragma unroll
      for (int n = 0; n < 8; ++n)
        bfr[n] = ldsFrag(bcur, n * 16 + (lane & 15), bo);
#pragma unroll
      for (int m = 0; m < 4; ++m)
#pragma unroll
        for (int n = 0; n < 8; ++n)
          acc[m][n] = __builtin_amdgcn_mfma_f32_16x16x32_bf16(af[m][kk], bfr[n], acc[m][n], 0, 0, 0);
    }

    // epilogue: acc already = sim * 2*log2(e)  ->  exp2
    const int colChunk = colGroupBase + c * 128;
    if ((colChunk >> 8) == r) {   // this chunk contains diagonal cells
#pragma unroll
      for (int m = 0; m < 4; ++m) {
        const int grow = rowBase + wv * 64 + m * 16 + ((lane >> 4) << 2);
#pragma unroll
        for (int n = 0; n < 8; ++n) {
          const int gcol = colChunk + n * 16 + (lane & 15);
#pragma unroll
          for (int rr = 0; rr < 4; ++rr) {
            float e = exp2f(acc[m][n][rr]);
            if (grow + rr == gcol) e = 0.0f;
            sums[m][rr] += e;
          }
        }
      }
    } else {
#pragma unroll
      for (int m = 0; m < 4; ++m)
#pragma unroll
        for (int n = 0; n < 8; ++n)
#pragma unroll
          for (int rr = 0; rr < 4; ++rr)
            sums[m][rr] += exp2f(acc[m][n][rr]);
    }

    // next chunk's staging (issued ~5000 cycles ago) must be complete before
    // any wave reads it; only those 16 loads/wave are in flight here.
    asm volatile("s_waitcnt vmcnt(0)" ::: "memory");
    __builtin_amdgcn_s_barrier();
    __builtin_amdgcn_sched_barrier(0);
  }

  // write per-colgroup partial rowsums (no atomics; every slot written once)
#pragma unroll
  for (int m = 0; m < 4; ++m)
#pragma unroll
    for (int rr = 0; rr < 4; ++rr) {
      float v = sums[m][rr];
      v += __shfl_xor(v, 1, 64);
      v += __shfl_xor(v, 2, 64);
      v += __shfl_xor(v, 4, 64);
      v += __shfl_xor(v, 8, 64);
      if ((lane & 15) == 0)
        part[(size_t)s * NROWS + rowBase + wv * 64 + m * 16 + ((lane >> 4) << 2) + rr] = v;
    }
}

// ---------------- kernel 3: loss = mean(log(sum_s part[s][i]) - pos[i])
__global__ __launch_bounds__(1024) void k_finalize(const float* __restrict__ part,
                                                   const float* __restrict__ pos,
                                                   float* __restrict__ out) {
  const int t = threadIdx.x;
  float s = 0.0f;
  for (int i = t; i < NROWS; i += 1024) {
    float d = 0.0f;
#pragma unroll
    for (int g = 0; g < 8; ++g) d += part[(size_t)g * NROWS + i];
    s += __logf(d) - pos[i];
  }
#pragma unroll
  for (int m = 1; m < 64; m <<= 1) s += __shfl_xor(s, m, 64);
  __shared__ float ps[16];
  if ((t & 63) == 0) ps[t >> 6] = s;
  __syncthreads();
  if (t == 0) {
    float tot = 0.0f;
#pragma unroll
    for (int i = 0; i < 16; ++i) tot += ps[i];
    out[0] = tot * (1.0f / (float)NROWS);
  }
}

extern "C" void kernel_launch(void* const* d_in, const int* in_sizes, int n_in,
                              void* d_out, int out_size, void* d_ws, size_t ws_size,
                              hipStream_t stream) {
  const float* zi = (const float*)d_in[0];
  const float* zj = (const float*)d_in[1];
  float* out = (float*)d_out;

  char* ws = (char*)d_ws;
  unsigned short* zn = (unsigned short*)ws;                        // 4 MiB bf16 (scaled)
  float* pos  = (float*)(ws + (size_t)NROWS * DIMK * 2);           // 32 KB
  float* part = pos + NROWS;                                       // 8 x 8192 x 4 = 256 KB

  k_normpos<<<HALFB / 4, 256, 0, stream>>>(zi, zj, zn, pos);
  k_simexp<<<256, 256, 0, stream>>>(zn, part);
  k_finalize<<<1, 1024, 0, stream>>>(part, pos, out);
}